// Round 1
// baseline (257.362 us; speedup 1.0000x reference)
//
#include <hip/hip_runtime.h>

// 9x9 box-sum (R=4), zero-padded, over 128 fp32 planes of 512x512.
// Pure streaming: no LDS, no barriers. Thread = 4 cols x 16 rows.
// Horizontal 9-sum in registers from 3 overlapping float4 loads (L1-merged),
// vertical 9-sum via register ring + running sum.
//
// R1 change vs baseline: RR 32 -> 16 (strips 16 -> 32 per image), grid 1024 -> 2048
// blocks, __launch_bounds__(256, 8). Doubles waves/SIMD 4 -> 8 to hide load latency
// (baseline: VALUBusy 10%, occupancy 37%, HBM 2.5/8 TB/s => latency-bound).
// Extra cost: vertical read redundancy 1.25x -> 1.5x, absorbed by L2/L3.

#define W   512
#define RR  16          // output rows per thread strip
#define NSTRIP (W / RR) // 32

__device__ __forceinline__ float4 ld4(const float* p) { return *(const float4*)p; }
__device__ __forceinline__ float4 add4(float4 a, float4 b) {
    return make_float4(a.x + b.x, a.y + b.y, a.z + b.z, a.w + b.w);
}
__device__ __forceinline__ float4 sub4(float4 a, float4 b) {
    return make_float4(a.x - b.x, a.y - b.y, a.z - b.z, a.w - b.w);
}

__global__ __launch_bounds__(256, 8) void boxfilter9(const float* __restrict__ in,
                                                     float* __restrict__ out) {
    const int t     = threadIdx.x;
    const int unit  = blockIdx.x * 2 + (t >> 7);   // img*NSTRIP + strip  (wave-uniform)
    const int img   = unit / NSTRIP;
    const int strip = unit % NSTRIP;
    const int cg    = t & 127;
    const int c0    = cg << 2;                     // output col base (multiple of 4)

    const float* __restrict__ inp  = in  + (size_t)img * W * W;
    float* __restrict__       outp = out + (size_t)img * W * W;
    const int  y0    = strip * RR;
    const bool has_l = (c0 >= 4);
    const bool has_r = (c0 + 4 < W);

    // horizontal 9-sum of input row y for cols c0..c0+3 (zero pad outside image)
    auto compute_h = [&](int y) -> float4 {
        float4 h;
        if ((unsigned)y < W) {                      // wave-uniform branch
            const float* row = inp + y * W;
            float4 a = has_l ? ld4(row + c0 - 4) : make_float4(0, 0, 0, 0);
            float4 b = ld4(row + c0);
            float4 c = has_r ? ld4(row + c0 + 4) : make_float4(0, 0, 0, 0);
            float s0 = ((a.x + a.y) + (a.z + a.w)) +
                       (((b.x + b.y) + (b.z + b.w)) + c.x);
            h.x = s0;
            h.y = s0  - a.x + c.y;
            h.z = h.y - a.y + c.z;
            h.w = h.z - a.z + c.w;
        } else {
            h = make_float4(0, 0, 0, 0);
        }
        return h;
    };

    // init: ring[0..7] = h(y0-4 .. y0+3), vsum = their sum (8 rows of the window)
    float4 ring[9];
    float4 vsum = make_float4(0, 0, 0, 0);
    #pragma unroll
    for (int k = 0; k < 8; ++k) {
        ring[k] = compute_h(y0 - 4 + k);
        vsum = add4(vsum, ring[k]);
    }

    // RR output rows; full unroll -> static ring indices, deep load pipelining
    #pragma unroll
    for (int i = 0; i < RR; ++i) {
        float4 hn = compute_h(y0 + 4 + i);         // bottom row of window
        float4 o  = add4(vsum, hn);                // 9-row total
        *(float4*)(outp + (size_t)(y0 + i) * W + c0) = o;
        vsum = sub4(o, ring[i % 9]);               // drop top row for next step
        ring[(i + 8) % 9] = hn;
    }
}

extern "C" void kernel_launch(void* const* d_in, const int* in_sizes, int n_in,
                              void* d_out, int out_size, void* d_ws, size_t ws_size,
                              hipStream_t stream) {
    const float* x = (const float*)d_in[0];
    float* y = (float*)d_out;
    // 128 images x 32 strips = 4096 units, 2 units per 256-thread block
    dim3 grid(128 * NSTRIP / 2);
    dim3 block(256);
    boxfilter9<<<grid, block, 0, stream>>>(x, y);
}

// Round 2
// 256.069 us; speedup vs baseline: 1.0050x; 1.0050x over previous
//
#include <hip/hip_runtime.h>

// 9x9 box-sum (R=4), zero-padded, over 128 fp32 planes of 512x512.
// Pure streaming: no LDS, no barriers. Thread = 4 cols x 16 rows.
// Horizontal 9-sum in registers from 3 overlapping float4 loads (L1-merged),
// vertical 9-sum via register ring + running sum.
//
// R2 change vs R1: keep RR=16 / grid=2048 (8192 waves = 8/SIMD available), but
// __launch_bounds__ back to (256, 4). R1's (256,8) capped the allocator at 64
// VGPRs -> ring spilled to scratch (VGPR 56->32, +12MB HBM writes, dur 86->105).
// The second launch_bounds arg only constrains the ALLOCATOR; with natural ~56
// VGPRs the hardware residences 8 waves/SIMD anyway (8*56=448 <= 512).

#define W   512
#define RR  16          // output rows per thread strip
#define NSTRIP (W / RR) // 32

__device__ __forceinline__ float4 ld4(const float* p) { return *(const float4*)p; }
__device__ __forceinline__ float4 add4(float4 a, float4 b) {
    return make_float4(a.x + b.x, a.y + b.y, a.z + b.z, a.w + b.w);
}
__device__ __forceinline__ float4 sub4(float4 a, float4 b) {
    return make_float4(a.x - b.x, a.y - b.y, a.z - b.z, a.w - b.w);
}

__global__ __launch_bounds__(256, 4) void boxfilter9(const float* __restrict__ in,
                                                     float* __restrict__ out) {
    const int t     = threadIdx.x;
    const int unit  = blockIdx.x * 2 + (t >> 7);   // img*NSTRIP + strip  (wave-uniform)
    const int img   = unit / NSTRIP;
    const int strip = unit % NSTRIP;
    const int cg    = t & 127;
    const int c0    = cg << 2;                     // output col base (multiple of 4)

    const float* __restrict__ inp  = in  + (size_t)img * W * W;
    float* __restrict__       outp = out + (size_t)img * W * W;
    const int  y0    = strip * RR;
    const bool has_l = (c0 >= 4);
    const bool has_r = (c0 + 4 < W);

    // horizontal 9-sum of input row y for cols c0..c0+3 (zero pad outside image)
    auto compute_h = [&](int y) -> float4 {
        float4 h;
        if ((unsigned)y < W) {                      // wave-uniform branch
            const float* row = inp + y * W;
            float4 a = has_l ? ld4(row + c0 - 4) : make_float4(0, 0, 0, 0);
            float4 b = ld4(row + c0);
            float4 c = has_r ? ld4(row + c0 + 4) : make_float4(0, 0, 0, 0);
            float s0 = ((a.x + a.y) + (a.z + a.w)) +
                       (((b.x + b.y) + (b.z + b.w)) + c.x);
            h.x = s0;
            h.y = s0  - a.x + c.y;
            h.z = h.y - a.y + c.z;
            h.w = h.z - a.z + c.w;
        } else {
            h = make_float4(0, 0, 0, 0);
        }
        return h;
    };

    // init: ring[0..7] = h(y0-4 .. y0+3), vsum = their sum (8 rows of the window)
    float4 ring[9];
    float4 vsum = make_float4(0, 0, 0, 0);
    #pragma unroll
    for (int k = 0; k < 8; ++k) {
        ring[k] = compute_h(y0 - 4 + k);
        vsum = add4(vsum, ring[k]);
    }

    // RR output rows; full unroll -> static ring indices, deep load pipelining
    #pragma unroll
    for (int i = 0; i < RR; ++i) {
        float4 hn = compute_h(y0 + 4 + i);         // bottom row of window
        float4 o  = add4(vsum, hn);                // 9-row total
        *(float4*)(outp + (size_t)(y0 + i) * W + c0) = o;
        vsum = sub4(o, ring[i % 9]);               // drop top row for next step
        ring[(i + 8) % 9] = hn;
    }
}

extern "C" void kernel_launch(void* const* d_in, const int* in_sizes, int n_in,
                              void* d_out, int out_size, void* d_ws, size_t ws_size,
                              hipStream_t stream) {
    const float* x = (const float*)d_in[0];
    float* y = (float*)d_out;
    // 128 images x 32 strips = 4096 units, 2 units per 256-thread block
    dim3 grid(128 * NSTRIP / 2);
    dim3 block(256);
    boxfilter9<<<grid, block, 0, stream>>>(x, y);
}